// Round 1
// baseline (3417.574 us; speedup 1.0000x reference)
//
#include <hip/hip_runtime.h>
#include <hip/hip_bf16.h>

#define SS 2048
#define HH 64
#define OO 2

__device__ __forceinline__ float readlane_f(float v, int l) {
    return __int_as_float(__builtin_amdgcn_readlane(__float_as_int(v), l));
}
__device__ __forceinline__ float fast_tanh(float x) {
    float ax = fabsf(x);
    float e = __expf(-2.0f * ax);
    float r = (1.0f - e) / (1.0f + e);
    return copysignf(r, x);
}
__device__ __forceinline__ float fast_sigmoid(float x) {
    return 1.0f / (1.0f + __expf(-x));
}

__global__ __launch_bounds__(256, 1) void pgjanet_kernel(
    const float* __restrict__ x,     // [B,S,2]
    const float* __restrict__ h0,    // [1,B,H]
    const float* __restrict__ Wa,    // [65,64]
    const float* __restrict__ ba,    // [64]
    const float* __restrict__ Wp1,   // [65,64]
    const float* __restrict__ bp1,
    const float* __restrict__ Wp2,   // [65,64]
    const float* __restrict__ bp2,
    const float* __restrict__ Wz,    // [128,64]
    const float* __restrict__ bz,
    const float* __restrict__ Wh,    // [128,64]
    const float* __restrict__ bh,
    const float* __restrict__ Wout,  // [64,2]
    const float* __restrict__ bout,  // [2]
    float* __restrict__ out)         // [B,S,2]
{
    const int b    = blockIdx.x;
    const int tid  = threadIdx.x;
    const int lane = tid & 63;
    const int wid  = tid >> 6;
    const int j    = lane;

    __shared__ __align__(16) float xs[SS * 2];      // 16 KB raw I/Q
    __shared__ __align__(16) float hbuf[32][HH];    // 8 KB output stash
    __shared__ __align__(16) float hL[2][HH];       // double-buffered h
    __shared__ __align__(16) float aL[HH];
    __shared__ __align__(16) float p1L[HH];
    __shared__ __align__(16) float p2L[HH];
    __shared__ __align__(16) float hzL[HH];
    __shared__ __align__(16) float hhp[4][HH];      // hh partials per wave
    __shared__ __align__(16) float pzL[2][HH];
    __shared__ __align__(16) float phL[2][HH];
    __shared__ __align__(16) float WoutL[HH * OO];
    __shared__ float boutL[OO];

    // ---- stage x[b] into LDS (coalesced float4) ----
    {
        const float4* xb4 = (const float4*)(x + (size_t)b * SS * 2);
        float4* xs4 = (float4*)xs;
        #pragma unroll
        for (int i = 0; i < (SS * 2 / 4) / 256; ++i)
            xs4[tid + i * 256] = xb4[tid + i * 256];
    }
    if (tid < HH * OO) WoutL[tid] = Wout[tid];
    if (tid < OO) boutL[tid] = bout[tid];

    // ---- initial hidden state ----
    float hreg = h0[b * HH + lane];
    if (wid == 0) hL[0][j] = hreg;

    // ---- per-wave weight columns into registers ----
    // Phase A task: w0:Wa-gate  w1:Wp1-gate  w2:Wp2-gate  w3: h@Wz[64:]
    const float* Aptr;
    float wrow0, bA;
    if (wid == 0)      { Aptr = Wa  + HH; wrow0 = Wa[j];  bA = ba[j];  }
    else if (wid == 1) { Aptr = Wp1 + HH; wrow0 = Wp1[j]; bA = bp1[j]; }
    else if (wid == 2) { Aptr = Wp2 + HH; wrow0 = Wp2[j]; bA = bp2[j]; }
    else               { Aptr = Wz + 64 * HH; wrow0 = 0.f; bA = 0.f;   }

    float wA[64];
    #pragma unroll
    for (int k = 0; k < 64; ++k) wA[k] = Aptr[k * HH + j];

    // T5 slice: wave w holds Wh[64+16w .. 64+16w+15][j]
    float wT5[16];
    #pragma unroll
    for (int k = 0; k < 16; ++k) wT5[k] = Wh[(64 + wid * 16 + k) * HH + j];

    // Phase B task: w0:Wz k0-31  w1:Wz k32-63  w2:Wh k0-31  w3:Wh k32-63
    const float* Bptr = (wid < 2 ? Wz : Wh) + (wid & 1) * 32 * HH;
    float wB[32];
    #pragma unroll
    for (int k = 0; k < 32; ++k) wB[k] = Bptr[k * HH + j];

    const float bzr = bz[j];
    const float bhr = bh[j];

    __syncthreads();

    int cur = 0;
    for (int t = 0; t < SS; ++t) {
        // ---- per-step scalar inputs (amp / cos / sin) ----
        const float xi = xs[2 * t];
        const float xq = xs[2 * t + 1];
        const float d  = xi * xi + xq * xq;
        float scal;
        if (wid == 0)      scal = sqrtf(d);
        else if (wid == 1) scal = (d > 0.f) ? xi / sqrtf(d) : 1.0f;
        else if (wid == 2) scal = (d > 0.f) ? xq / sqrtf(d) : 0.0f;
        else               scal = 0.f;

        // ---- PHASE A: gate/hz matvec (64 FMA) + hh slice (16 FMA) ----
        const float4* h4 = (const float4*)hL[cur];
        float a0 = 0.f, a1 = 0.f, a2 = 0.f, a3 = 0.f;
        #pragma unroll
        for (int k4 = 0; k4 < 16; ++k4) {
            float4 hv = h4[k4];
            a0 += hv.x * wA[4 * k4 + 0];
            a1 += hv.y * wA[4 * k4 + 1];
            a2 += hv.z * wA[4 * k4 + 2];
            a3 += hv.w * wA[4 * k4 + 3];
        }
        float accA = (a0 + a1) + (a2 + a3) + scal * wrow0 + bA;

        float t0 = 0.f, t1 = 0.f, t2 = 0.f, t3 = 0.f;
        #pragma unroll
        for (int k4 = 0; k4 < 4; ++k4) {
            float4 hv = h4[wid * 4 + k4];
            t0 += hv.x * wT5[4 * k4 + 0];
            t1 += hv.y * wT5[4 * k4 + 1];
            t2 += hv.z * wT5[4 * k4 + 2];
            t3 += hv.w * wT5[4 * k4 + 3];
        }
        hhp[wid][j] = (t0 + t1) + (t2 + t3);

        if (wid == 0)      aL[j]  = fast_tanh(accA);
        else if (wid == 1) p1L[j] = fast_tanh(accA);
        else if (wid == 2) p2L[j] = fast_tanh(accA);
        else               hzL[j] = accA;
        __syncthreads();  // bar1: gates + hz + hh partials visible

        // ---- u (redundant per lane, no extra barrier) ----
        {
            const float av  = aL[j];
            const float p1v = p1L[j];
            const float p2v = p2L[j];
            float u = av * p1v * p2v * (1.f - av) * (1.f - p1v) * (1.f - p2v);

            // ---- PHASE B: 32-k half of u@Wz / u@Wh via readlane broadcast ----
            const int kbase = (wid & 1) * 32;
            float b0 = 0.f, b1 = 0.f, b2 = 0.f, b3 = 0.f;
            #pragma unroll
            for (int k = 0; k < 32; k += 4) {
                b0 += readlane_f(u, kbase + k + 0) * wB[k + 0];
                b1 += readlane_f(u, kbase + k + 1) * wB[k + 1];
                b2 += readlane_f(u, kbase + k + 2) * wB[k + 2];
                b3 += readlane_f(u, kbase + k + 3) * wB[k + 3];
            }
            float accB = (b0 + b1) + (b2 + b3);
            if (wid < 2) pzL[wid][j] = accB;
            else         phL[wid - 2][j] = accB;
        }
        __syncthreads();  // bar2: pz/ph partials visible

        // ---- COMBINE (all waves redundantly) ----
        {
            float zpre = pzL[0][j] + pzL[1][j] + hzL[j] + bzr;
            float z = fast_sigmoid(zpre);
            float hpre = phL[0][j] + phL[1][j]
                       + ((hhp[0][j] + hhp[1][j]) + (hhp[2][j] + hhp[3][j]))
                       + bhr;
            float hc = fast_tanh(hpre);
            float hn = z * hreg + (1.f - z) * hc;
            hreg = hn;
            if (wid == 0) {
                hL[cur ^ 1][j] = hn;
                hbuf[t & 31][j] = hn;
            }
        }
        cur ^= 1;
        __syncthreads();  // bar3: h(t+1) + hbuf row visible

        // ---- output flush every 32 steps: [32,64]@[64,2] over 256 lanes ----
        if ((t & 31) == 31) {
            const int tt = tid >> 3;          // 0..31
            const int o  = (tid >> 2) & 1;    // 0..1
            const int kb = (tid & 3) * 16;
            float acc = 0.f;
            #pragma unroll
            for (int k = 0; k < 16; ++k)
                acc += hbuf[tt][kb + k] * WoutL[(kb + k) * OO + o];
            acc += __shfl_xor(acc, 1);
            acc += __shfl_xor(acc, 2);
            if ((tid & 3) == 0)
                out[((size_t)b * SS + (t - 31 + tt)) * OO + o] = acc + boutL[o];
            // safe: next hbuf[0] write happens after bar1+bar2 of step t+1
        }
    }
}

extern "C" void kernel_launch(void* const* d_in, const int* in_sizes, int n_in,
                              void* d_out, int out_size, void* d_ws, size_t ws_size,
                              hipStream_t stream) {
    const float* x    = (const float*)d_in[0];
    const float* h0   = (const float*)d_in[1];
    const float* Wa   = (const float*)d_in[2];
    const float* ba   = (const float*)d_in[3];
    const float* Wp1  = (const float*)d_in[4];
    const float* bp1  = (const float*)d_in[5];
    const float* Wp2  = (const float*)d_in[6];
    const float* bp2  = (const float*)d_in[7];
    const float* Wz   = (const float*)d_in[8];
    const float* bz   = (const float*)d_in[9];
    const float* Wh   = (const float*)d_in[10];
    const float* bh   = (const float*)d_in[11];
    const float* Wout = (const float*)d_in[12];
    const float* bout = (const float*)d_in[13];
    float* out = (float*)d_out;

    pgjanet_kernel<<<256, 256, 0, stream>>>(x, h0, Wa, ba, Wp1, bp1, Wp2, bp2,
                                            Wz, bz, Wh, bh, Wout, bout, out);
}

// Round 2
// 2822.786 us; speedup vs baseline: 1.2107x; 1.2107x over previous
//
#include <hip/hip_runtime.h>

#define SS 2048
#define HH 64
#define OO 2

__device__ __forceinline__ float readlane_f(float v, int l) {
    return __int_as_float(__builtin_amdgcn_readlane(__float_as_int(v), l));
}
__device__ __forceinline__ float fast_tanh(float x) {
    float ax = fabsf(x);
    float e = __expf(-2.0f * ax);
    float r = (1.0f - e) * __builtin_amdgcn_rcpf(1.0f + e);
    return copysignf(r, x);
}
__device__ __forceinline__ float fast_sigmoid(float x) {
    return __builtin_amdgcn_rcpf(1.0f + __expf(-x));
}

// load 4 strided weight-column elements into a named float4
#define LD4(V, P, K)                                                        \
    float4 V = make_float4((P)[(K) * HH + j], (P)[((K) + 1) * HH + j],      \
                           (P)[((K) + 2) * HH + j], (P)[((K) + 3) * HH + j])

#define MACA(I, W)                          \
    {                                       \
        float4 hv = h4[(I)];                \
        a0 = fmaf(hv.x, W.x, a0);           \
        a1 = fmaf(hv.y, W.y, a1);           \
        a2 = fmaf(hv.z, W.z, a2);           \
        a3 = fmaf(hv.w, W.w, a3);           \
    }

#define MACT(I, W)                          \
    {                                       \
        float4 hv = h4w[(I)];               \
        t0 = fmaf(hv.x, W.x, t0);           \
        t1 = fmaf(hv.y, W.y, t1);           \
        t2 = fmaf(hv.z, W.z, t2);           \
        t3 = fmaf(hv.w, W.w, t3);           \
    }

#define MACB(K, W)                                               \
    {                                                            \
        b0 = fmaf(readlane_f(u, kbase + (K) + 0), W.x, b0);      \
        b1 = fmaf(readlane_f(u, kbase + (K) + 1), W.y, b1);      \
        b2 = fmaf(readlane_f(u, kbase + (K) + 2), W.z, b2);      \
        b3 = fmaf(readlane_f(u, kbase + (K) + 3), W.w, b3);      \
    }

__global__ __launch_bounds__(256, 1) void pgjanet_kernel(
    const float* __restrict__ x,     // [B,S,2]
    const float* __restrict__ h0,    // [1,B,H]
    const float* __restrict__ Wa,    // [65,64]
    const float* __restrict__ ba,
    const float* __restrict__ Wp1,
    const float* __restrict__ bp1,
    const float* __restrict__ Wp2,
    const float* __restrict__ bp2,
    const float* __restrict__ Wz,    // [128,64]
    const float* __restrict__ bz,
    const float* __restrict__ Wh,    // [128,64]
    const float* __restrict__ bh,
    const float* __restrict__ Wout,  // [64,2]
    const float* __restrict__ bout,
    float* __restrict__ out)         // [B,S,2]
{
    const int b    = blockIdx.x;
    const int tid  = threadIdx.x;
    const int lane = tid & 63;
    const int wid  = tid >> 6;
    const int j    = lane;

    __shared__ float ampL[SS];                     // 8 KB
    __shared__ float cosL[SS];                     // 8 KB
    __shared__ float sinL[SS];                     // 8 KB
    __shared__ __align__(16) float hbuf[32][HH + 1]; // padded: conflict-free
    __shared__ __align__(16) float hL[2][HH];
    __shared__ __align__(16) float aL[HH];
    __shared__ __align__(16) float p1L[HH];
    __shared__ __align__(16) float p2L[HH];
    __shared__ __align__(16) float hzL[HH];
    __shared__ __align__(16) float hhp[4][HH];
    __shared__ __align__(16) float pzL[2][HH];
    __shared__ __align__(16) float phL[2][HH];
    __shared__ float WoutL[HH * OO];
    __shared__ float boutL[OO];

    // ---- precompute amp / cos / sin tables (one pass, coalesced) ----
    {
        const float2* xb = (const float2*)(x + (size_t)b * SS * 2);
        #pragma unroll
        for (int it = 0; it < SS / 256; ++it) {
            int i = tid + it * 256;
            float2 v = xb[i];
            float d = v.x * v.x + v.y * v.y;
            float r = sqrtf(d);
            float inv = (d > 0.f) ? __builtin_amdgcn_rcpf(r) : 0.f;
            ampL[i] = r;
            cosL[i] = (d > 0.f) ? v.x * inv : 1.0f;
            sinL[i] = v.y * inv;  // d==0 -> inv==0 -> 0
        }
    }
    if (tid < HH * OO) WoutL[tid] = Wout[tid];
    if (tid < OO) boutL[tid] = bout[tid];

    float hreg = h0[b * HH + lane];
    if (wid == 0) hL[0][j] = hreg;

    // ---- per-wave phase-A weight columns (named float4s, no arrays) ----
    const float* Aptr;
    const float* scalP;
    float wrow0, bA;
    if (wid == 0)      { Aptr = Wa  + HH;      wrow0 = Wa[j];  bA = ba[j];  scalP = ampL; }
    else if (wid == 1) { Aptr = Wp1 + HH;      wrow0 = Wp1[j]; bA = bp1[j]; scalP = cosL; }
    else if (wid == 2) { Aptr = Wp2 + HH;      wrow0 = Wp2[j]; bA = bp2[j]; scalP = sinL; }
    else               { Aptr = Wz + 64 * HH;  wrow0 = 0.f;    bA = 0.f;    scalP = ampL; }

    LD4(wa0,  Aptr, 0);  LD4(wa1,  Aptr, 4);  LD4(wa2,  Aptr, 8);  LD4(wa3,  Aptr, 12);
    LD4(wa4,  Aptr, 16); LD4(wa5,  Aptr, 20); LD4(wa6,  Aptr, 24); LD4(wa7,  Aptr, 28);
    LD4(wa8,  Aptr, 32); LD4(wa9,  Aptr, 36); LD4(wa10, Aptr, 40); LD4(wa11, Aptr, 44);
    LD4(wa12, Aptr, 48); LD4(wa13, Aptr, 52); LD4(wa14, Aptr, 56); LD4(wa15, Aptr, 60);

    // hh slice: wave w owns Wh rows [64+16w, 64+16w+16)
    const float* Tptr = Wh + (64 + wid * 16) * HH;
    LD4(wt0, Tptr, 0); LD4(wt1, Tptr, 4); LD4(wt2, Tptr, 8); LD4(wt3, Tptr, 12);

    // phase-B: w0:Wz k0-31  w1:Wz k32-63  w2:Wh k0-31  w3:Wh k32-63
    const float* Bptr = (wid < 2 ? Wz : Wh) + (wid & 1) * 32 * HH;
    LD4(wb0, Bptr, 0);  LD4(wb1, Bptr, 4);  LD4(wb2, Bptr, 8);  LD4(wb3, Bptr, 12);
    LD4(wb4, Bptr, 16); LD4(wb5, Bptr, 20); LD4(wb6, Bptr, 24); LD4(wb7, Bptr, 28);

    const float bzr = bz[j];
    const float bhr = bh[j];
    const int kbase = (wid & 1) * 32;

    __syncthreads();

    int cur = 0;
    for (int t = 0; t < SS; ++t) {
        const float scal = scalP[t];

        // ---- PHASE A: 64-MAC gate/hz matvec + 16-MAC hh slice ----
        const float4* h4  = (const float4*)hL[cur];
        const float4* h4w = h4 + wid * 4;

        float a0 = 0.f, a1 = 0.f, a2 = 0.f, a3 = 0.f;
        MACA(0, wa0)   MACA(1, wa1)   MACA(2, wa2)   MACA(3, wa3)
        MACA(4, wa4)   MACA(5, wa5)   MACA(6, wa6)   MACA(7, wa7)
        MACA(8, wa8)   MACA(9, wa9)   MACA(10, wa10) MACA(11, wa11)
        MACA(12, wa12) MACA(13, wa13) MACA(14, wa14) MACA(15, wa15)
        float accA = (a0 + a1) + (a2 + a3) + fmaf(scal, wrow0, bA);

        float t0 = 0.f, t1 = 0.f, t2 = 0.f, t3 = 0.f;
        MACT(0, wt0) MACT(1, wt1) MACT(2, wt2) MACT(3, wt3)
        hhp[wid][j] = (t0 + t1) + (t2 + t3);

        if (wid == 0)      aL[j]  = fast_tanh(accA);
        else if (wid == 1) p1L[j] = fast_tanh(accA);
        else if (wid == 2) p2L[j] = fast_tanh(accA);
        else               hzL[j] = accA;
        __syncthreads();  // bar1

        // ---- u (redundant per lane) + PHASE B 32-MAC via readlane ----
        {
            const float av  = aL[j];
            const float p1v = p1L[j];
            const float p2v = p2L[j];
            float u = av * p1v * p2v * (1.f - av) * (1.f - p1v) * (1.f - p2v);

            float b0 = 0.f, b1 = 0.f, b2 = 0.f, b3 = 0.f;
            MACB(0, wb0)  MACB(4, wb1)  MACB(8, wb2)  MACB(12, wb3)
            MACB(16, wb4) MACB(20, wb5) MACB(24, wb6) MACB(28, wb7)
            float accB = (b0 + b1) + (b2 + b3);
            if (wid < 2) pzL[wid][j] = accB;
            else         phL[wid - 2][j] = accB;
        }
        __syncthreads();  // bar2

        // ---- COMBINE (all waves redundantly) ----
        {
            float zpre = pzL[0][j] + pzL[1][j] + hzL[j] + bzr;
            float z = fast_sigmoid(zpre);
            float hpre = phL[0][j] + phL[1][j]
                       + ((hhp[0][j] + hhp[1][j]) + (hhp[2][j] + hhp[3][j]))
                       + bhr;
            float hc = fast_tanh(hpre);
            float hn = fmaf(z, hreg - hc, hc);
            hreg = hn;
            if (wid == 0) {
                hL[cur ^ 1][j] = hn;
                hbuf[t & 31][j] = hn;
            }
        }
        cur ^= 1;
        __syncthreads();  // bar3

        // ---- output flush every 32 steps: [32,64]@[64,2] over 256 lanes ----
        if ((t & 31) == 31) {
            const int tt = tid >> 3;          // 0..31
            const int kq = (tid >> 1) & 3;    // k-quarter, within-wave bits
            const int o  = tid & 1;           // 0..1
            const int kb = kq * 16;
            float acc = 0.f;
            #pragma unroll
            for (int k = 0; k < 16; ++k)
                acc += hbuf[tt][kb + k] * WoutL[(kb + k) * OO + o];
            acc += __shfl_xor(acc, 2);
            acc += __shfl_xor(acc, 4);
            if (kq == 0)
                out[((size_t)b * SS + (t - 31 + tt)) * OO + o] = acc + boutL[o];
            // safe: next hbuf[0] write happens after bar1+bar2 of step t+1
        }
    }
}

extern "C" void kernel_launch(void* const* d_in, const int* in_sizes, int n_in,
                              void* d_out, int out_size, void* d_ws, size_t ws_size,
                              hipStream_t stream) {
    const float* x    = (const float*)d_in[0];
    const float* h0   = (const float*)d_in[1];
    const float* Wa   = (const float*)d_in[2];
    const float* ba   = (const float*)d_in[3];
    const float* Wp1  = (const float*)d_in[4];
    const float* bp1  = (const float*)d_in[5];
    const float* Wp2  = (const float*)d_in[6];
    const float* bp2  = (const float*)d_in[7];
    const float* Wz   = (const float*)d_in[8];
    const float* bz   = (const float*)d_in[9];
    const float* Wh   = (const float*)d_in[10];
    const float* bh   = (const float*)d_in[11];
    const float* Wout = (const float*)d_in[12];
    const float* bout = (const float*)d_in[13];
    float* out = (float*)d_out;

    pgjanet_kernel<<<256, 256, 0, stream>>>(x, h0, Wa, ba, Wp1, bp1, Wp2, bp2,
                                            Wz, bz, Wh, bh, Wout, bout, out);
}

// Round 3
// 2766.024 us; speedup vs baseline: 1.2356x; 1.0205x over previous
//
#include <hip/hip_runtime.h>

#define SS 2048
#define HH 64
#define OO 2

__device__ __forceinline__ float readlane_f(float v, int l) {
    return __int_as_float(__builtin_amdgcn_readlane(__float_as_int(v), l));
}
__device__ __forceinline__ float fast_tanh(float x) {
    float ax = fabsf(x);
    float e = __expf(-2.0f * ax);
    float r = (1.0f - e) * __builtin_amdgcn_rcpf(1.0f + e);
    return copysignf(r, x);
}
__device__ __forceinline__ float fast_sigmoid(float x) {
    return __builtin_amdgcn_rcpf(1.0f + __expf(-x));
}

// load 4 strided weight-column elements into a named float4
#define LD4(V, P, K)                                                        \
    float4 V = make_float4((P)[(K) * HH + j], (P)[((K) + 1) * HH + j],      \
                           (P)[((K) + 2) * HH + j], (P)[((K) + 3) * HH + j])

#define MACA(I, W)                          \
    {                                       \
        float4 hv = h4[(I)];                \
        a0 = fmaf(hv.x, W.x, a0);           \
        a1 = fmaf(hv.y, W.y, a1);           \
        a2 = fmaf(hv.z, W.z, a2);           \
        a3 = fmaf(hv.w, W.w, a3);           \
    }

#define MACT(I, W)                          \
    {                                       \
        float4 hv = h4w[(I)];               \
        t0 = fmaf(hv.x, W.x, t0);           \
        t1 = fmaf(hv.y, W.y, t1);           \
        t2 = fmaf(hv.z, W.z, t2);           \
        t3 = fmaf(hv.w, W.w, t3);           \
    }

#define MACB(K, W)                                               \
    {                                                            \
        b0 = fmaf(readlane_f(u, kbase + (K) + 0), W.x, b0);      \
        b1 = fmaf(readlane_f(u, kbase + (K) + 1), W.y, b1);      \
        b2 = fmaf(readlane_f(u, kbase + (K) + 2), W.z, b2);      \
        b3 = fmaf(readlane_f(u, kbase + (K) + 3), W.w, b3);      \
    }

__global__ __launch_bounds__(256)
__attribute__((amdgpu_waves_per_eu(1, 1)))
void pgjanet_kernel(
    const float* __restrict__ x,     // [B,S,2]
    const float* __restrict__ h0,    // [1,B,H]
    const float* __restrict__ Wa,    // [65,64]
    const float* __restrict__ ba,
    const float* __restrict__ Wp1,
    const float* __restrict__ bp1,
    const float* __restrict__ Wp2,
    const float* __restrict__ bp2,
    const float* __restrict__ Wz,    // [128,64]
    const float* __restrict__ bz,
    const float* __restrict__ Wh,    // [128,64]
    const float* __restrict__ bh,
    const float* __restrict__ Wout,  // [64,2]
    const float* __restrict__ bout,
    float* __restrict__ out)         // [B,S,2]
{
    const int b    = blockIdx.x;
    const int tid  = threadIdx.x;
    const int lane = tid & 63;
    const int wid  = tid >> 6;
    const int j    = lane;

    __shared__ float ampL[SS];                     // 8 KB
    __shared__ float cosL[SS];                     // 8 KB
    __shared__ float sinL[SS];                     // 8 KB
    __shared__ __align__(16) float hbuf[32][HH + 1]; // padded: conflict-free
    __shared__ __align__(16) float hL[2][HH];
    __shared__ __align__(16) float aL[HH];
    __shared__ __align__(16) float p1L[HH];
    __shared__ __align__(16) float p2L[HH];
    __shared__ __align__(16) float hzL[HH];
    __shared__ __align__(16) float hhp[4][HH];
    __shared__ __align__(16) float pzL[2][HH];
    __shared__ __align__(16) float phL[2][HH];
    __shared__ float WoutL[HH * OO];
    __shared__ float boutL[OO];

    // ---- precompute amp / cos / sin tables (one pass, coalesced) ----
    {
        const float2* xb = (const float2*)(x + (size_t)b * SS * 2);
        #pragma unroll
        for (int it = 0; it < SS / 256; ++it) {
            int i = tid + it * 256;
            float2 v = xb[i];
            float d = v.x * v.x + v.y * v.y;
            float r = sqrtf(d);
            float inv = (d > 0.f) ? __builtin_amdgcn_rcpf(r) : 0.f;
            ampL[i] = r;
            cosL[i] = (d > 0.f) ? v.x * inv : 1.0f;
            sinL[i] = v.y * inv;  // d==0 -> inv==0 -> 0
        }
    }
    if (tid < HH * OO) WoutL[tid] = Wout[tid];
    if (tid < OO) boutL[tid] = bout[tid];

    float hreg = h0[b * HH + lane];
    if (wid == 0) hL[0][j] = hreg;

    // ---- per-wave phase-A weight columns (named float4s, no arrays) ----
    const float* Aptr;
    const float* scalP;
    float wrow0, bA;
    if (wid == 0)      { Aptr = Wa  + HH;      wrow0 = Wa[j];  bA = ba[j];  scalP = ampL; }
    else if (wid == 1) { Aptr = Wp1 + HH;      wrow0 = Wp1[j]; bA = bp1[j]; scalP = cosL; }
    else if (wid == 2) { Aptr = Wp2 + HH;      wrow0 = Wp2[j]; bA = bp2[j]; scalP = sinL; }
    else               { Aptr = Wz + 64 * HH;  wrow0 = 0.f;    bA = 0.f;    scalP = ampL; }

    LD4(wa0,  Aptr, 0);  LD4(wa1,  Aptr, 4);  LD4(wa2,  Aptr, 8);  LD4(wa3,  Aptr, 12);
    LD4(wa4,  Aptr, 16); LD4(wa5,  Aptr, 20); LD4(wa6,  Aptr, 24); LD4(wa7,  Aptr, 28);
    LD4(wa8,  Aptr, 32); LD4(wa9,  Aptr, 36); LD4(wa10, Aptr, 40); LD4(wa11, Aptr, 44);
    LD4(wa12, Aptr, 48); LD4(wa13, Aptr, 52); LD4(wa14, Aptr, 56); LD4(wa15, Aptr, 60);

    // hh slice: wave w owns Wh rows [64+16w, 64+16w+16)
    const float* Tptr = Wh + (64 + wid * 16) * HH;
    LD4(wt0, Tptr, 0); LD4(wt1, Tptr, 4); LD4(wt2, Tptr, 8); LD4(wt3, Tptr, 12);

    // phase-B: w0:Wz k0-31  w1:Wz k32-63  w2:Wh k0-31  w3:Wh k32-63
    const float* Bptr = (wid < 2 ? Wz : Wh) + (wid & 1) * 32 * HH;
    LD4(wb0, Bptr, 0);  LD4(wb1, Bptr, 4);  LD4(wb2, Bptr, 8);  LD4(wb3, Bptr, 12);
    LD4(wb4, Bptr, 16); LD4(wb5, Bptr, 20); LD4(wb6, Bptr, 24); LD4(wb7, Bptr, 28);

    const float bzr = bz[j];
    const float bhr = bh[j];
    const int kbase = (wid & 1) * 32;

    __syncthreads();

    int cur = 0;
    for (int t = 0; t < SS; ++t) {
        const float scal = scalP[t];

        // ---- PHASE A: 64-MAC gate/hz matvec + 16-MAC hh slice ----
        const float4* h4  = (const float4*)hL[cur];
        const float4* h4w = h4 + wid * 4;

        float a0 = 0.f, a1 = 0.f, a2 = 0.f, a3 = 0.f;
        MACA(0, wa0)   MACA(1, wa1)   MACA(2, wa2)   MACA(3, wa3)
        MACA(4, wa4)   MACA(5, wa5)   MACA(6, wa6)   MACA(7, wa7)
        MACA(8, wa8)   MACA(9, wa9)   MACA(10, wa10) MACA(11, wa11)
        MACA(12, wa12) MACA(13, wa13) MACA(14, wa14) MACA(15, wa15)
        float accA = (a0 + a1) + (a2 + a3) + fmaf(scal, wrow0, bA);

        float t0 = 0.f, t1 = 0.f, t2 = 0.f, t3 = 0.f;
        MACT(0, wt0) MACT(1, wt1) MACT(2, wt2) MACT(3, wt3)
        hhp[wid][j] = (t0 + t1) + (t2 + t3);

        if (wid == 0)      aL[j]  = fast_tanh(accA);
        else if (wid == 1) p1L[j] = fast_tanh(accA);
        else if (wid == 2) p2L[j] = fast_tanh(accA);
        else               hzL[j] = accA;
        __syncthreads();  // bar1

        // ---- u (redundant per lane) + PHASE B 32-MAC via readlane ----
        {
            const float av  = aL[j];
            const float p1v = p1L[j];
            const float p2v = p2L[j];
            float u = av * p1v * p2v * (1.f - av) * (1.f - p1v) * (1.f - p2v);

            float b0 = 0.f, b1 = 0.f, b2 = 0.f, b3 = 0.f;
            MACB(0, wb0)  MACB(4, wb1)  MACB(8, wb2)  MACB(12, wb3)
            MACB(16, wb4) MACB(20, wb5) MACB(24, wb6) MACB(28, wb7)
            float accB = (b0 + b1) + (b2 + b3);
            if (wid < 2) pzL[wid][j] = accB;
            else         phL[wid - 2][j] = accB;
        }
        __syncthreads();  // bar2

        // ---- COMBINE (all waves redundantly) ----
        {
            float zpre = pzL[0][j] + pzL[1][j] + hzL[j] + bzr;
            float z = fast_sigmoid(zpre);
            float hpre = phL[0][j] + phL[1][j]
                       + ((hhp[0][j] + hhp[1][j]) + (hhp[2][j] + hhp[3][j]))
                       + bhr;
            float hc = fast_tanh(hpre);
            float hn = fmaf(z, hreg - hc, hc);
            hreg = hn;
            if (wid == 0) {
                hL[cur ^ 1][j] = hn;
                hbuf[t & 31][j] = hn;
            }
        }
        cur ^= 1;
        __syncthreads();  // bar3

        // ---- output flush every 32 steps: [32,64]@[64,2] over 256 lanes ----
        if ((t & 31) == 31) {
            const int tt = tid >> 3;          // 0..31
            const int kq = (tid >> 1) & 3;    // k-quarter, within-wave bits
            const int o  = tid & 1;           // 0..1
            const int kb = kq * 16;
            float acc = 0.f;
            #pragma unroll
            for (int k = 0; k < 16; ++k)
                acc += hbuf[tt][kb + k] * WoutL[(kb + k) * OO + o];
            acc += __shfl_xor(acc, 2);
            acc += __shfl_xor(acc, 4);
            if (kq == 0)
                out[((size_t)b * SS + (t - 31 + tt)) * OO + o] = acc + boutL[o];
            // safe: next hbuf[0] write happens after bar1+bar2 of step t+1
        }
    }
}

extern "C" void kernel_launch(void* const* d_in, const int* in_sizes, int n_in,
                              void* d_out, int out_size, void* d_ws, size_t ws_size,
                              hipStream_t stream) {
    const float* x    = (const float*)d_in[0];
    const float* h0   = (const float*)d_in[1];
    const float* Wa   = (const float*)d_in[2];
    const float* ba   = (const float*)d_in[3];
    const float* Wp1  = (const float*)d_in[4];
    const float* bp1  = (const float*)d_in[5];
    const float* Wp2  = (const float*)d_in[6];
    const float* bp2  = (const float*)d_in[7];
    const float* Wz   = (const float*)d_in[8];
    const float* bz   = (const float*)d_in[9];
    const float* Wh   = (const float*)d_in[10];
    const float* bh   = (const float*)d_in[11];
    const float* Wout = (const float*)d_in[12];
    const float* bout = (const float*)d_in[13];
    float* out = (float*)d_out;

    pgjanet_kernel<<<256, 256, 0, stream>>>(x, h0, Wa, ba, Wp1, bp1, Wp2, bp2,
                                            Wz, bz, Wh, bh, Wout, bout, out);
}

// Round 4
// 2300.877 us; speedup vs baseline: 1.4853x; 1.2022x over previous
//
#include <hip/hip_runtime.h>

#define SS 2048
#define HH 64
#define OO 2

__device__ __forceinline__ float readlane_f(float v, int l) {
    return __int_as_float(__builtin_amdgcn_readlane(__float_as_int(v), l));
}
__device__ __forceinline__ float fast_tanh(float x) {
    float ax = fabsf(x);
    float e = __expf(-2.0f * ax);
    float r = (1.0f - e) * __builtin_amdgcn_rcpf(1.0f + e);
    return copysignf(r, x);
}
__device__ __forceinline__ float fast_sigmoid(float x) {
    return __builtin_amdgcn_rcpf(1.0f + __expf(-x));
}

// load 4 strided weight-column elements into a named float4
#define LD4(V, P, K)                                                        \
    float4 V = make_float4((P)[(K) * HH + j], (P)[((K) + 1) * HH + j],      \
                           (P)[((K) + 2) * HH + j], (P)[((K) + 3) * HH + j])

#define MACA(I, W)                          \
    {                                       \
        float4 hv = h4h[(I)];               \
        a0 = fmaf(hv.x, W.x, a0);           \
        a1 = fmaf(hv.y, W.y, a1);           \
        a2 = fmaf(hv.z, W.z, a2);           \
        a3 = fmaf(hv.w, W.w, a3);           \
    }

#define MACT(I, W)                          \
    {                                       \
        float4 hv = h4t[(I)];               \
        t0 = fmaf(hv.x, W.x, t0);           \
        t1 = fmaf(hv.y, W.y, t1);           \
        t2 = fmaf(hv.z, W.z, t2);           \
        t3 = fmaf(hv.w, W.w, t3);           \
    }

#define MACB(K, W)                                               \
    {                                                            \
        b0 = fmaf(readlane_f(u, kbase + (K) + 0), W.x, b0);      \
        b1 = fmaf(readlane_f(u, kbase + (K) + 1), W.y, b1);      \
        b2 = fmaf(readlane_f(u, kbase + (K) + 2), W.z, b2);      \
        b3 = fmaf(readlane_f(u, kbase + (K) + 3), W.w, b3);      \
    }

__global__ __launch_bounds__(512, 2) void pgjanet_kernel(
    const float* __restrict__ x,     // [B,S,2]
    const float* __restrict__ h0,    // [1,B,H]
    const float* __restrict__ Wa,    // [65,64]
    const float* __restrict__ ba,
    const float* __restrict__ Wp1,
    const float* __restrict__ bp1,
    const float* __restrict__ Wp2,
    const float* __restrict__ bp2,
    const float* __restrict__ Wz,    // [128,64]
    const float* __restrict__ bz,
    const float* __restrict__ Wh,    // [128,64]
    const float* __restrict__ bh,
    const float* __restrict__ Wout,  // [64,2]
    const float* __restrict__ bout,
    float* __restrict__ out)         // [B,S,2]
{
    const int b    = blockIdx.x;
    const int tid  = threadIdx.x;    // 0..511
    const int lane = tid & 63;
    const int wid  = tid >> 6;       // 0..7
    const int j    = lane;
    const int gidx = wid >> 1;       // 0:a 1:p1 2:p2 3:hz
    const int half = wid & 1;        // k-half of the gate matvec

    __shared__ float ampL[SS];                       // 8 KB
    __shared__ float cosL[SS];                       // 8 KB
    __shared__ float sinL[SS];                       // 8 KB
    __shared__ __align__(16) float hbuf[32][HH + 1]; // padded
    __shared__ __align__(16) float hL[2][HH];
    __shared__ __align__(16) float gp[4][2][HH];     // raw gate/hz half-partials
    __shared__ __align__(16) float hhp[8][HH];       // h@Wh[64:] 8-row partials
    __shared__ __align__(16) float pB[8][HH];        // phase-B partials (folded)
    __shared__ float WoutL[HH * OO];
    __shared__ float boutL[OO];

    // ---- precompute amp / cos / sin tables (coalesced, once) ----
    {
        const float2* xb = (const float2*)(x + (size_t)b * SS * 2);
        #pragma unroll
        for (int it = 0; it < SS / 512; ++it) {
            int i = tid + it * 512;
            float2 v = xb[i];
            float d = v.x * v.x + v.y * v.y;
            float r = sqrtf(d);
            float inv = (d > 0.f) ? __builtin_amdgcn_rcpf(r) : 0.f;
            ampL[i] = r;
            cosL[i] = (d > 0.f) ? v.x * inv : 1.0f;
            sinL[i] = v.y * inv;
        }
    }
    if (tid < HH * OO) WoutL[tid] = Wout[tid];
    if (tid < OO) boutL[tid] = bout[tid];

    float hreg = h0[b * HH + lane];
    if (wid == 0) hL[0][j] = hreg;

    // ---- phase-A weights: 32-k half of one matvec (8 float4) ----
    const float* Grow;
    const float* scalP = ampL;
    float wrow0 = 0.f, bA = 0.f;
    if (gidx == 0) {
        Grow = Wa + (1 + half * 32) * HH; scalP = ampL;
        if (half == 0) { wrow0 = Wa[j]; bA = ba[j]; }
    } else if (gidx == 1) {
        Grow = Wp1 + (1 + half * 32) * HH; scalP = cosL;
        if (half == 0) { wrow0 = Wp1[j]; bA = bp1[j]; }
    } else if (gidx == 2) {
        Grow = Wp2 + (1 + half * 32) * HH; scalP = sinL;
        if (half == 0) { wrow0 = Wp2[j]; bA = bp2[j]; }
    } else {
        Grow = Wz + (64 + half * 32) * HH;   // hz: h @ Wz[64:]
    }
    LD4(wv0, Grow, 0);  LD4(wv1, Grow, 4);  LD4(wv2, Grow, 8);  LD4(wv3, Grow, 12);
    LD4(wv4, Grow, 16); LD4(wv5, Grow, 20); LD4(wv6, Grow, 24); LD4(wv7, Grow, 28);

    // ---- hh slice: rows [64+8*wid, 64+8*wid+8) of Wh (2 float4) ----
    const float* Trow = Wh + (64 + wid * 8) * HH;
    LD4(wt0, Trow, 0); LD4(wt1, Trow, 4);

    // ---- phase-B weights: 16-k slice of u@Wz (w0-3) / u@Wh (w4-7) ----
    const float* Brow = (wid < 4 ? Wz : Wh) + ((wid & 3) * 16) * HH;
    LD4(wb0, Brow, 0); LD4(wb1, Brow, 4); LD4(wb2, Brow, 8); LD4(wb3, Brow, 12);
    const int kbase = (wid & 3) * 16;

    const float bzr = bz[j];
    const float bhr = bh[j];

    __syncthreads();

    int cur = 0;
    for (int t = 0; t < SS; ++t) {
        const float scal = scalP[t];

        // ---- PHASE A: 32-MAC half-matvec + 8-MAC hh slice ----
        const float4* h4h = (const float4*)hL[cur] + half * 8;
        float a0 = 0.f, a1 = 0.f, a2 = 0.f, a3 = 0.f;
        MACA(0, wv0) MACA(1, wv1) MACA(2, wv2) MACA(3, wv3)
        MACA(4, wv4) MACA(5, wv5) MACA(6, wv6) MACA(7, wv7)
        gp[gidx][half][j] = (a0 + a1) + (a2 + a3) + fmaf(scal, wrow0, bA);

        const float4* h4t = (const float4*)(hL[cur] + wid * 8);
        float t0 = 0.f, t1 = 0.f, t2 = 0.f, t3 = 0.f;
        MACT(0, wt0) MACT(1, wt1)
        const float hh_own = (t0 + t1) + (t2 + t3);
        hhp[wid][j] = hh_own;
        __syncthreads();  // bar1

        // ---- u (redundant per wave) + PHASE B 16-MAC via readlane ----
        {
            const float av  = fast_tanh(gp[0][0][j] + gp[0][1][j]);
            const float p1v = fast_tanh(gp[1][0][j] + gp[1][1][j]);
            const float p2v = fast_tanh(gp[2][0][j] + gp[2][1][j]);
            float u = av * p1v * p2v * (1.f - av) * (1.f - p1v) * (1.f - p2v);

            float b0 = 0.f, b1 = 0.f, b2 = 0.f, b3 = 0.f;
            MACB(0, wb0) MACB(4, wb1) MACB(8, wb2) MACB(12, wb3)
            float accB = (b0 + b1) + (b2 + b3);
            // fold: w0/w1 add the hz halves; w4-7 add own + mate hh partials
            if (wid < 2)       accB += gp[3][wid][j];
            else if (wid >= 4) accB += hh_own + hhp[wid - 4][j];
            pB[wid][j] = accB;
        }
        __syncthreads();  // bar2

        // ---- COMBINE (all waves redundantly) ----
        {
            float zpre = ((pB[0][j] + pB[1][j]) + (pB[2][j] + pB[3][j])) + bzr;
            float z = fast_sigmoid(zpre);
            float hpre = ((pB[4][j] + pB[5][j]) + (pB[6][j] + pB[7][j])) + bhr;
            float hc = fast_tanh(hpre);
            float hn = fmaf(z, hreg - hc, hc);
            hreg = hn;
            if (wid == 0) {
                hL[cur ^ 1][j] = hn;
                hbuf[t & 31][j] = hn;
            }
        }
        cur ^= 1;
        __syncthreads();  // bar3

        // ---- output flush every 32 steps: [32,64]@[64,2] over 512 lanes ----
        if ((t & 31) == 31) {
            const int tt = tid >> 4;          // 0..31
            const int s  = tid & 15;
            const int o  = s & 1;             // 0..1
            const int kq = s >> 1;            // 0..7
            const int kb = kq * 8;
            float acc = 0.f;
            #pragma unroll
            for (int k = 0; k < 8; ++k)
                acc += hbuf[tt][kb + k] * WoutL[(kb + k) * OO + o];
            acc += __shfl_xor(acc, 2);
            acc += __shfl_xor(acc, 4);
            acc += __shfl_xor(acc, 8);
            if (kq == 0)
                out[((size_t)b * SS + (t - 31 + tt)) * OO + o] = acc + boutL[o];
            // safe: hbuf[0] next written after bar1+bar2 of step t+1
        }
    }
}

extern "C" void kernel_launch(void* const* d_in, const int* in_sizes, int n_in,
                              void* d_out, int out_size, void* d_ws, size_t ws_size,
                              hipStream_t stream) {
    const float* x    = (const float*)d_in[0];
    const float* h0   = (const float*)d_in[1];
    const float* Wa   = (const float*)d_in[2];
    const float* ba   = (const float*)d_in[3];
    const float* Wp1  = (const float*)d_in[4];
    const float* bp1  = (const float*)d_in[5];
    const float* Wp2  = (const float*)d_in[6];
    const float* bp2  = (const float*)d_in[7];
    const float* Wz   = (const float*)d_in[8];
    const float* bz   = (const float*)d_in[9];
    const float* Wh   = (const float*)d_in[10];
    const float* bh   = (const float*)d_in[11];
    const float* Wout = (const float*)d_in[12];
    const float* bout = (const float*)d_in[13];
    float* out = (float*)d_out;

    pgjanet_kernel<<<256, 512, 0, stream>>>(x, h0, Wa, ba, Wp1, bp1, Wp2, bp2,
                                            Wz, bz, Wh, bh, Wout, bout, out);
}

// Round 5
// 2294.046 us; speedup vs baseline: 1.4898x; 1.0030x over previous
//
#include <hip/hip_runtime.h>

#define SS 2048
#define HH 64
#define OO 2

__device__ __forceinline__ float readlane_f(float v, int l) {
    return __int_as_float(__builtin_amdgcn_readlane(__float_as_int(v), l));
}
__device__ __forceinline__ float fast_tanh(float x) {
    float ax = fabsf(x);
    float e = __expf(-2.0f * ax);
    float r = (1.0f - e) * __builtin_amdgcn_rcpf(1.0f + e);
    return copysignf(r, x);
}
__device__ __forceinline__ float fast_sigmoid(float x) {
    return __builtin_amdgcn_rcpf(1.0f + __expf(-x));
}

// load 4 strided weight-column elements into a named float4
#define LD4(V, P, K)                                                        \
    float4 V = make_float4((P)[(K) * HH + j], (P)[((K) + 1) * HH + j],      \
                           (P)[((K) + 2) * HH + j], (P)[((K) + 3) * HH + j])

#define MACA(I, W)                          \
    {                                       \
        float4 hv = h4h[(I)];               \
        a0 = fmaf(hv.x, W.x, a0);           \
        a1 = fmaf(hv.y, W.y, a1);           \
        a2 = fmaf(hv.z, W.z, a2);           \
        a3 = fmaf(hv.w, W.w, a3);           \
    }

#define MACT(I, W)                          \
    {                                       \
        float4 hv = h4t[(I)];               \
        t0 = fmaf(hv.x, W.x, t0);           \
        t1 = fmaf(hv.y, W.y, t1);           \
        t2 = fmaf(hv.z, W.z, t2);           \
        t3 = fmaf(hv.w, W.w, t3);           \
    }

#define MACB(K, W)                                               \
    {                                                            \
        b0 = fmaf(readlane_f(u, kbase + (K) + 0), W.x, b0);      \
        b1 = fmaf(readlane_f(u, kbase + (K) + 1), W.y, b1);      \
        b2 = fmaf(readlane_f(u, kbase + (K) + 2), W.z, b2);      \
        b3 = fmaf(readlane_f(u, kbase + (K) + 3), W.w, b3);      \
    }

__global__ __launch_bounds__(512)
__attribute__((amdgpu_waves_per_eu(2, 2)))
void pgjanet_kernel(
    const float* __restrict__ x,     // [B,S,2]
    const float* __restrict__ h0,    // [1,B,H]
    const float* __restrict__ Wa,    // [65,64]
    const float* __restrict__ ba,
    const float* __restrict__ Wp1,
    const float* __restrict__ bp1,
    const float* __restrict__ Wp2,
    const float* __restrict__ bp2,
    const float* __restrict__ Wz,    // [128,64]
    const float* __restrict__ bz,
    const float* __restrict__ Wh,    // [128,64]
    const float* __restrict__ bh,
    const float* __restrict__ Wout,  // [64,2]
    const float* __restrict__ bout,
    float* __restrict__ out)         // [B,S,2]
{
    const int b    = blockIdx.x;
    const int tid  = threadIdx.x;    // 0..511
    const int lane = tid & 63;
    const int wid  = tid >> 6;       // 0..7
    const int j    = lane;
    const int gidx = wid >> 1;       // 0:a 1:p1 2:p2 3:hz
    const int half = wid & 1;        // k-half of the gate matvec

    __shared__ float ampL[SS];                       // 8 KB
    __shared__ float cosL[SS];                       // 8 KB
    __shared__ float sinL[SS];                       // 8 KB
    __shared__ __align__(16) float hbuf[32][HH + 1]; // padded
    __shared__ __align__(16) float hL[2][HH];
    __shared__ __align__(16) float gp[4][2][HH];     // raw gate/hz half-partials
    __shared__ __align__(16) float hhp[8][HH];       // h@Wh[64:] 8-row partials
    __shared__ __align__(16) float pB[8][HH];        // phase-B partials (folded)
    __shared__ float WoutL[HH * OO];
    __shared__ float boutL[OO];

    // ---- precompute amp / cos / sin tables (coalesced, once) ----
    {
        const float2* xb = (const float2*)(x + (size_t)b * SS * 2);
        #pragma unroll
        for (int it = 0; it < SS / 512; ++it) {
            int i = tid + it * 512;
            float2 v = xb[i];
            float d = v.x * v.x + v.y * v.y;
            float r = sqrtf(d);
            float inv = (d > 0.f) ? __builtin_amdgcn_rcpf(r) : 0.f;
            ampL[i] = r;
            cosL[i] = (d > 0.f) ? v.x * inv : 1.0f;
            sinL[i] = v.y * inv;
        }
    }
    if (tid < HH * OO) WoutL[tid] = Wout[tid];
    if (tid < OO) boutL[tid] = bout[tid];

    float hreg = h0[b * HH + lane];
    if (wid == 0) hL[0][j] = hreg;

    // ---- phase-A weights: 32-k half of one matvec (8 float4) ----
    const float* Grow;
    const float* scalP = ampL;
    float wrow0 = 0.f, bA = 0.f;
    if (gidx == 0) {
        Grow = Wa + (1 + half * 32) * HH; scalP = ampL;
        if (half == 0) { wrow0 = Wa[j]; bA = ba[j]; }
    } else if (gidx == 1) {
        Grow = Wp1 + (1 + half * 32) * HH; scalP = cosL;
        if (half == 0) { wrow0 = Wp1[j]; bA = bp1[j]; }
    } else if (gidx == 2) {
        Grow = Wp2 + (1 + half * 32) * HH; scalP = sinL;
        if (half == 0) { wrow0 = Wp2[j]; bA = bp2[j]; }
    } else {
        Grow = Wz + (64 + half * 32) * HH;   // hz: h @ Wz[64:]
    }
    LD4(wv0, Grow, 0);  LD4(wv1, Grow, 4);  LD4(wv2, Grow, 8);  LD4(wv3, Grow, 12);
    LD4(wv4, Grow, 16); LD4(wv5, Grow, 20); LD4(wv6, Grow, 24); LD4(wv7, Grow, 28);

    // ---- hh slice: rows [64+8*wid, 64+8*wid+8) of Wh (2 float4) ----
    const float* Trow = Wh + (64 + wid * 8) * HH;
    LD4(wt0, Trow, 0); LD4(wt1, Trow, 4);

    // ---- phase-B weights: 16-k slice of u@Wz (w0-3) / u@Wh (w4-7) ----
    const float* Brow = (wid < 4 ? Wz : Wh) + ((wid & 3) * 16) * HH;
    LD4(wb0, Brow, 0); LD4(wb1, Brow, 4); LD4(wb2, Brow, 8); LD4(wb3, Brow, 12);
    const int kbase = (wid & 3) * 16;

    const float bzr = bz[j];
    const float bhr = bh[j];

    __syncthreads();

    int cur = 0;
    for (int t = 0; t < SS; ++t) {
        const float scal = scalP[t];

        // ---- PHASE A: 32-MAC half-matvec + 8-MAC hh slice ----
        const float4* h4h = (const float4*)hL[cur] + half * 8;
        float a0 = 0.f, a1 = 0.f, a2 = 0.f, a3 = 0.f;
        MACA(0, wv0) MACA(1, wv1) MACA(2, wv2) MACA(3, wv3)
        MACA(4, wv4) MACA(5, wv5) MACA(6, wv6) MACA(7, wv7)
        gp[gidx][half][j] = (a0 + a1) + (a2 + a3) + fmaf(scal, wrow0, bA);

        const float4* h4t = (const float4*)(hL[cur] + wid * 8);
        float t0 = 0.f, t1 = 0.f, t2 = 0.f, t3 = 0.f;
        MACT(0, wt0) MACT(1, wt1)
        const float hh_own = (t0 + t1) + (t2 + t3);
        hhp[wid][j] = hh_own;
        __syncthreads();  // bar1

        // ---- u (redundant per wave) + PHASE B 16-MAC via readlane ----
        {
            const float av  = fast_tanh(gp[0][0][j] + gp[0][1][j]);
            const float p1v = fast_tanh(gp[1][0][j] + gp[1][1][j]);
            const float p2v = fast_tanh(gp[2][0][j] + gp[2][1][j]);
            float u = av * p1v * p2v * (1.f - av) * (1.f - p1v) * (1.f - p2v);

            float b0 = 0.f, b1 = 0.f, b2 = 0.f, b3 = 0.f;
            MACB(0, wb0) MACB(4, wb1) MACB(8, wb2) MACB(12, wb3)
            float accB = (b0 + b1) + (b2 + b3);
            // fold: w0/w1 add the hz halves; w4-7 add own + mate hh partials
            if (wid < 2)       accB += gp[3][wid][j];
            else if (wid >= 4) accB += hh_own + hhp[wid - 4][j];
            pB[wid][j] = accB;
        }
        __syncthreads();  // bar2

        // ---- COMBINE (all waves redundantly) ----
        {
            float zpre = ((pB[0][j] + pB[1][j]) + (pB[2][j] + pB[3][j])) + bzr;
            float z = fast_sigmoid(zpre);
            float hpre = ((pB[4][j] + pB[5][j]) + (pB[6][j] + pB[7][j])) + bhr;
            float hc = fast_tanh(hpre);
            float hn = fmaf(z, hreg - hc, hc);
            hreg = hn;
            if (wid == 0) {
                hL[cur ^ 1][j] = hn;
                hbuf[t & 31][j] = hn;
            }
        }
        cur ^= 1;
        __syncthreads();  // bar3

        // ---- output flush every 32 steps: [32,64]@[64,2] over 512 lanes ----
        if ((t & 31) == 31) {
            const int tt = tid >> 4;          // 0..31
            const int s  = tid & 15;
            const int o  = s & 1;             // 0..1
            const int kq = s >> 1;            // 0..7
            const int kb = kq * 8;
            float acc = 0.f;
            #pragma unroll
            for (int k = 0; k < 8; ++k)
                acc += hbuf[tt][kb + k] * WoutL[(kb + k) * OO + o];
            acc += __shfl_xor(acc, 2);
            acc += __shfl_xor(acc, 4);
            acc += __shfl_xor(acc, 8);
            if (kq == 0)
                out[((size_t)b * SS + (t - 31 + tt)) * OO + o] = acc + boutL[o];
            // safe: hbuf[0] next written after bar1+bar2 of step t+1
        }
    }
}

extern "C" void kernel_launch(void* const* d_in, const int* in_sizes, int n_in,
                              void* d_out, int out_size, void* d_ws, size_t ws_size,
                              hipStream_t stream) {
    const float* x    = (const float*)d_in[0];
    const float* h0   = (const float*)d_in[1];
    const float* Wa   = (const float*)d_in[2];
    const float* ba   = (const float*)d_in[3];
    const float* Wp1  = (const float*)d_in[4];
    const float* bp1  = (const float*)d_in[5];
    const float* Wp2  = (const float*)d_in[6];
    const float* bp2  = (const float*)d_in[7];
    const float* Wz   = (const float*)d_in[8];
    const float* bz   = (const float*)d_in[9];
    const float* Wh   = (const float*)d_in[10];
    const float* bh   = (const float*)d_in[11];
    const float* Wout = (const float*)d_in[12];
    const float* bout = (const float*)d_in[13];
    float* out = (float*)d_out;

    pgjanet_kernel<<<256, 512, 0, stream>>>(x, h0, Wa, ba, Wp1, bp1, Wp2, bp2,
                                            Wz, bz, Wh, bh, Wout, bout, out);
}